// Round 1
// baseline (200.654 us; speedup 1.0000x reference)
//
#include <hip/hip_runtime.h>
#include <hip/hip_bf16.h>

#define BB 8
#define NN 256
#define CC 32
#define LL 4
#define BN (BB*NN)          // 2048
#define LC (LL*CC)          // 128

// ---------------- Kernel A: precompute q, k, vals ----------------
__global__ __launch_bounds__(192) void so3_pre(
    const float* __restrict__ xg,   // (B,N,4)
    const float* __restrict__ Wq,   // (4,32)
    const float* __restrict__ Wk,   // (4,32)
    const float* __restrict__ Wv,   // (L,4,32)
    float* __restrict__ qg,         // (B,N,32)
    float* __restrict__ kg,         // (B,N,32)
    float* __restrict__ valsg)      // (L,B,N,32)
{
    const int row = blockIdx.x;     // b*N + j
    const int t = threadIdx.x;
    const float x0 = xg[row*4+0], x1 = xg[row*4+1], x2 = xg[row*4+2], x3 = xg[row*4+3];
    if (t < 64) {
        const float* W = (t < 32) ? Wq : Wk;
        const int c = t & 31;
        float a = x0*W[c] + x1*W[32+c] + x2*W[64+c] + x3*W[96+c];
        if (t < 32) qg[row*32+c] = a; else kg[row*32+c] = a;
    } else {
        const int idx = t - 64;                 // 0..127
        const int l = idx >> 5, c = idx & 31;
        const float* W = Wv + l*128;            // (4,32) slab
        float a = x0*W[c] + x1*W[32+c] + x2*W[64+c] + x3*W[96+c];
        valsg[(l*BN + row)*CC + c] = a;
    }
}

// ---------------- Kernel B: main per-(b,i) ----------------
__global__ __launch_bounds__(128) void so3_main(
    const float* __restrict__ xg,     // (B,N,4)
    const float* __restrict__ qg,     // (B,N,32)
    const float* __restrict__ kg,     // (B,N,32)
    const float* __restrict__ valsg,  // (L,B,N,32)
    const float* __restrict__ Rw1,    // (32)
    const float* __restrict__ Rb1,    // (32)
    const float* __restrict__ Rw2,    // (32,128)
    const float* __restrict__ Rb2,    // (128)
    float* __restrict__ invg)         // (B,N,128)
{
    const int tid = threadIdx.x;          // 0..127 == lc
    const int bi = blockIdx.x;            // b*N + i
    const int b = bi >> 8;
    const int rowbase = b * NN;

    __shared__ float alpha[NN];
    __shared__ float qs[CC];
    __shared__ __align__(16) float h_lds[8][CC];
    __shared__ float ys_lds[8][16];
    __shared__ float vals_lds[8][LC];
    __shared__ float red[4];

    // per-thread constants
    float rw2col[32];
    #pragma unroll
    for (int h = 0; h < 32; ++h) rw2col[h] = Rw2[h*LC + tid];
    const float rb2 = Rb2[tid];
    const int hh = tid & 31;
    const float rw1r = Rw1[hh], rb1r = Rb1[hh];

    const float cix = xg[bi*4+0], ciy = xg[bi*4+1], ciz = xg[bi*4+2];

    if (tid < 32) qs[tid] = qg[bi*32 + tid];
    __syncthreads();

    // logits for j = tid, tid+128
    float lg0, lg1;
    {
        float lv[2];
        #pragma unroll
        for (int rr = 0; rr < 2; ++rr) {
            const int j = tid + rr*128;
            const float4* krow = reinterpret_cast<const float4*>(&kg[(rowbase + j)*32]);
            float a = 0.f;
            #pragma unroll
            for (int c4 = 0; c4 < 8; ++c4) {
                float4 kv = krow[c4];
                a += kv.x*qs[c4*4+0] + kv.y*qs[c4*4+1] + kv.z*qs[c4*4+2] + kv.w*qs[c4*4+3];
            }
            lv[rr] = a * 0.17677669529663687f;  // 1/sqrt(32)
        }
        lg0 = lv[0]; lg1 = lv[1];
    }
    const int lane = tid & 63, wid = tid >> 6;
    float m = fmaxf(lg0, lg1);
    #pragma unroll
    for (int off = 32; off >= 1; off >>= 1) m = fmaxf(m, __shfl_xor(m, off));
    if (lane == 0) red[wid] = m;
    __syncthreads();
    m = fmaxf(red[0], red[1]);
    float e0 = __expf(lg0 - m), e1 = __expf(lg1 - m);
    float s = e0 + e1;
    #pragma unroll
    for (int off = 32; off >= 1; off >>= 1) s += __shfl_xor(s, off);
    __syncthreads();              // red reuse
    if (lane == 0) red[2+wid] = s;
    __syncthreads();
    const float inv_s = 1.0f / (red[2] + red[3]);
    alpha[tid]      = e0 * inv_s;
    alpha[tid+128]  = e1 * inv_s;

    float acc[7] = {0,0,0,0,0,0,0};
    const int l = tid >> 5;
    const int nm = 2*l + 1;
    const int ybase = l*l;

    for (int j0 = 0; j0 < NN; j0 += 8) {
        __syncthreads();   // protects LDS tiles (and alpha on first iter)

        // stage vals: (L,B,N,32) -> vals_lds[jj][tid]
        #pragma unroll
        for (int jj = 0; jj < 8; ++jj)
            vals_lds[jj][tid] = valsg[(l*BN + rowbase + j0 + jj)*CC + (tid & 31)];

        // stage Ys (threads 0..7, one j each)
        if (tid < 8) {
            const int j = j0 + tid;
            const float cjx = xg[(rowbase+j)*4+0];
            const float cjy = xg[(rowbase+j)*4+1];
            const float cjz = xg[(rowbase+j)*4+2];
            const float dx = cjx - cix, dy = cjy - ciy, dz = cjz - ciz;
            const float r2 = dx*dx + dy*dy + dz*dz + 1e-8f;
            const float ir = rsqrtf(r2);
            const float ux = dx*ir, uy = dy*ir, uz = dz*ir;
            const float X2 = ux*ux, Y2 = uy*uy, Z2 = uz*uz;
            float* Y = ys_lds[tid];
            Y[0]  = 0.28209479f;
            Y[1]  = 0.48860251f*uy;  Y[2] = 0.48860251f*uz;  Y[3] = 0.48860251f*ux;
            Y[4]  = 1.09254843f*ux*uy;
            Y[5]  = 1.09254843f*uy*uz;
            Y[6]  = 0.31539157f*(3.f*Z2 - 1.f);
            Y[7]  = 1.09254843f*ux*uz;
            Y[8]  = 0.54627422f*(X2 - Y2);
            Y[9]  = 0.59004359f*uy*(3.f*X2 - Y2);
            Y[10] = 2.89061144f*ux*uy*uz;
            Y[11] = 0.45704579f*uy*(5.f*Z2 - 1.f);
            Y[12] = 0.37317633f*uz*(5.f*Z2 - 3.f);
            Y[13] = 0.45704579f*ux*(5.f*Z2 - 1.f);
            Y[14] = 1.44530572f*uz*(X2 - Y2);
            Y[15] = 0.59004359f*ux*(X2 - 3.f*Y2);
        }

        // stage h: each thread covers (jj, hh) and (jj+4, hh)
        {
            const int jjb = tid >> 5;   // 0..3
            #pragma unroll
            for (int rep = 0; rep < 2; ++rep) {
                const int jj = jjb + rep*4;
                const int j = j0 + jj;
                const float cjx = xg[(rowbase+j)*4+0];
                const float cjy = xg[(rowbase+j)*4+1];
                const float cjz = xg[(rowbase+j)*4+2];
                const float dx = cjx - cix, dy = cjy - ciy, dz = cjz - ciz;
                const float r = sqrtf(dx*dx + dy*dy + dz*dz + 1e-8f);
                h_lds[jj][hh] = fmaxf(r*rw1r + rb1r, 0.f);
            }
        }
        __syncthreads();

        // accumulate 8 j's
        #pragma unroll
        for (int jj = 0; jj < 8; ++jj) {
            float R = rb2;
            const float4* hrow = reinterpret_cast<const float4*>(&h_lds[jj][0]);
            #pragma unroll
            for (int q8 = 0; q8 < 8; ++q8) {
                float4 hv = hrow[q8];
                R += hv.x*rw2col[q8*4+0] + hv.y*rw2col[q8*4+1]
                   + hv.z*rw2col[q8*4+2] + hv.w*rw2col[q8*4+3];
            }
            const float t = alpha[j0+jj] * R * vals_lds[jj][tid];
            const float* Y = &ys_lds[jj][ybase];
            #pragma unroll
            for (int mm = 0; mm < 7; ++mm)
                if (mm < nm) acc[mm] += t * Y[mm];
        }
    }

    float ssum = 1e-8f;
    #pragma unroll
    for (int mm = 0; mm < 7; ++mm)
        if (mm < nm) ssum += acc[mm]*acc[mm];
    invg[bi*LC + tid] = sqrtf(ssum);
}

// ---------------- Kernel C: pool + fc1 + LN + relu + fc2 ----------------
__global__ __launch_bounds__(256) void so3_post(
    const float* __restrict__ invg,   // (B,N,128)
    const float* __restrict__ fc1_w,  // (256,256)
    const float* __restrict__ fc1_b,  // (256)
    const float* __restrict__ ln_g,   // (256)
    const float* __restrict__ ln_b,   // (256)
    const float* __restrict__ fc2_w,  // (256,40)
    const float* __restrict__ fc2_b,  // (40)
    float* __restrict__ outg)         // (B,40)
{
    const int b = blockIdx.x;
    const int t = threadIdx.x;
    __shared__ float pooled[256];
    __shared__ float h1s[256];
    __shared__ float redA[4], redB[4];

    if (t < 128) {
        float mx = -1e30f, sm = 0.f;
        for (int i = 0; i < NN; ++i) {
            const float v = invg[(b*NN + i)*LC + t];
            mx = fmaxf(mx, v);
            sm += v;
        }
        pooled[t] = mx;
        pooled[128 + t] = sm * (1.f/256.f);
    }
    __syncthreads();

    float acc = fc1_b[t];
    for (int k = 0; k < 256; ++k)
        acc += pooled[k] * fc1_w[k*256 + t];

    // LayerNorm over 256 features (4 waves)
    const int lane = t & 63, wid = t >> 6;
    float s1 = acc, s2 = acc*acc;
    #pragma unroll
    for (int off = 32; off >= 1; off >>= 1) {
        s1 += __shfl_xor(s1, off);
        s2 += __shfl_xor(s2, off);
    }
    if (lane == 0) { redA[wid] = s1; redB[wid] = s2; }
    __syncthreads();
    s1 = redA[0]+redA[1]+redA[2]+redA[3];
    s2 = redB[0]+redB[1]+redB[2]+redB[3];
    const float mu = s1 * (1.f/256.f);
    const float var = s2 * (1.f/256.f) - mu*mu;
    float v = (acc - mu) * rsqrtf(var + 1e-5f) * ln_g[t] + ln_b[t];
    v = fmaxf(v, 0.f);
    h1s[t] = v;
    __syncthreads();

    if (t < 40) {
        float o = fc2_b[t];
        for (int k = 0; k < 256; ++k)
            o += h1s[k] * fc2_w[k*40 + t];
        outg[b*40 + t] = o;
    }
}

extern "C" void kernel_launch(void* const* d_in, const int* in_sizes, int n_in,
                              void* d_out, int out_size, void* d_ws, size_t ws_size,
                              hipStream_t stream) {
    const float* x     = (const float*)d_in[0];
    const float* Wq    = (const float*)d_in[1];
    const float* Wk    = (const float*)d_in[2];
    const float* Wv    = (const float*)d_in[3];
    const float* Rw1   = (const float*)d_in[4];
    const float* Rb1   = (const float*)d_in[5];
    const float* Rw2   = (const float*)d_in[6];
    const float* Rb2   = (const float*)d_in[7];
    const float* fc1_w = (const float*)d_in[8];
    const float* fc1_b = (const float*)d_in[9];
    const float* ln_g  = (const float*)d_in[10];
    const float* ln_b  = (const float*)d_in[11];
    const float* fc2_w = (const float*)d_in[12];
    const float* fc2_b = (const float*)d_in[13];
    float* out = (float*)d_out;

    float* ws = (float*)d_ws;
    float* qg    = ws;                    // 65536
    float* kg    = qg + BN*CC;            // 65536
    float* valsg = kg + BN*CC;            // 262144
    float* invg  = valsg + LL*BN*CC;      // 262144

    so3_pre <<<BN, 192, 0, stream>>>(x, Wq, Wk, Wv, qg, kg, valsg);
    so3_main<<<BN, 128, 0, stream>>>(x, qg, kg, valsg, Rw1, Rb1, Rw2, Rb2, invg);
    so3_post<<<BB, 256, 0, stream>>>(invg, fc1_w, fc1_b, ln_g, ln_b, fc2_w, fc2_b, out);
}

// Round 2
// 77.096 us; speedup vs baseline: 2.6026x; 2.6026x over previous
//
#include <hip/hip_runtime.h>
#include <hip/hip_bf16.h>

#define BB 8
#define NN 256
#define CC 32
#define LL 4
#define BN (BB*NN)          // 2048
#define LC (LL*CC)          // 128

typedef short short8 __attribute__((ext_vector_type(8)));
typedef float f32x4 __attribute__((ext_vector_type(4)));

__device__ inline short f2bf(float f){
    union { float f; unsigned u; } v; v.f = f;
    unsigned r = v.u + 0x7FFFu + ((v.u >> 16) & 1u);   // RNE to bf16
    return (short)(r >> 16);
}

// ---------------- Kernel A: precompute q, k, vals ----------------
__global__ __launch_bounds__(192) void so3_pre(
    const float* __restrict__ xg,   // (B,N,4)
    const float* __restrict__ Wq,   // (4,32)
    const float* __restrict__ Wk,   // (4,32)
    const float* __restrict__ Wv,   // (L,4,32)
    float* __restrict__ qg,         // (B,N,32)
    float* __restrict__ kg,         // (B,N,32)
    float* __restrict__ valsg)      // (L,B,N,32)
{
    const int row = blockIdx.x;     // b*N + j
    const int t = threadIdx.x;
    const float x0 = xg[row*4+0], x1 = xg[row*4+1], x2 = xg[row*4+2], x3 = xg[row*4+3];
    if (t < 64) {
        const float* W = (t < 32) ? Wq : Wk;
        const int c = t & 31;
        float a = x0*W[c] + x1*W[32+c] + x2*W[64+c] + x3*W[96+c];
        if (t < 32) qg[row*32+c] = a; else kg[row*32+c] = a;
    } else {
        const int idx = t - 64;                 // 0..127
        const int l = idx >> 5, c = idx & 31;
        const float* W = Wv + l*128;            // (4,32) slab
        float a = x0*W[c] + x1*W[32+c] + x2*W[64+c] + x3*W[96+c];
        valsg[(l*BN + row)*CC + c] = a;
    }
}

// ---------------- Kernel B: main per-(b,i), MFMA for R ----------------
__global__ __launch_bounds__(128) void so3_main(
    const float* __restrict__ xg,     // (B,N,4)
    const float* __restrict__ qg,     // (B,N,32)
    const float* __restrict__ kg,     // (B,N,32)
    const float* __restrict__ valsg,  // (L,B,N,32)
    const float* __restrict__ Rw1,    // (32)
    const float* __restrict__ Rb1,    // (32)
    const float* __restrict__ Rw2,    // (32,128)
    const float* __restrict__ Rb2,    // (128)
    float* __restrict__ invg)         // (B,N,128)
{
    const int tid = threadIdx.x;          // 0..127 == lc
    const int bi = blockIdx.x;            // b*N + i
    const int b = bi >> 8;
    const int rowbase = b * NN;
    const int lane = tid & 63;
    const int w = tid >> 6;               // wave 0/1

    __shared__ float alpha[NN];
    __shared__ float r_lds[NN];
    __shared__ float qs[CC];
    __shared__ __align__(16) float ys2[16][32];    // Y, 8 slots per l (zero-padded)
    __shared__ float R_lds[16][132];               // padded row stride (bank-spread)
    __shared__ float red[4];

    const int l = tid >> 5;
    const int c = tid & 31;
    const int nm = 2*l + 1;

    // zero ys2 once; per-tile writers only touch the nonzero slots
    ((float*)ys2)[tid]     = 0.f;
    ((float*)ys2)[tid+128] = 0.f;
    ((float*)ys2)[tid+256] = 0.f;
    ((float*)ys2)[tid+384] = 0.f;

    const float cix = xg[bi*4+0], ciy = xg[bi*4+1], ciz = xg[bi*4+2];

    // r precompute (2 j's per thread)
    #pragma unroll
    for (int rr = 0; rr < 2; ++rr) {
        const int j = tid + rr*128;
        const float dx = xg[(rowbase+j)*4+0] - cix;
        const float dy = xg[(rowbase+j)*4+1] - ciy;
        const float dz = xg[(rowbase+j)*4+2] - ciz;
        r_lds[j] = sqrtf(dx*dx + dy*dy + dz*dz + 1e-8f);
    }

    if (tid < 32) qs[tid] = qg[bi*32 + tid];
    __syncthreads();

    // ---- logits + softmax (j = tid, tid+128) ----
    float lg0, lg1;
    {
        float lv[2];
        #pragma unroll
        for (int rr = 0; rr < 2; ++rr) {
            const int j = tid + rr*128;
            const float4* krow = reinterpret_cast<const float4*>(&kg[(rowbase + j)*32]);
            float a = 0.f;
            #pragma unroll
            for (int c4 = 0; c4 < 8; ++c4) {
                float4 kv = krow[c4];
                a += kv.x*qs[c4*4+0] + kv.y*qs[c4*4+1] + kv.z*qs[c4*4+2] + kv.w*qs[c4*4+3];
            }
            lv[rr] = a * 0.17677669529663687f;  // 1/sqrt(32)
        }
        lg0 = lv[0]; lg1 = lv[1];
    }
    float m = fmaxf(lg0, lg1);
    #pragma unroll
    for (int off = 32; off >= 1; off >>= 1) m = fmaxf(m, __shfl_xor(m, off));
    if (lane == 0) red[w] = m;
    __syncthreads();
    m = fmaxf(red[0], red[1]);
    float e0 = __expf(lg0 - m), e1 = __expf(lg1 - m);
    float s = e0 + e1;
    #pragma unroll
    for (int off = 32; off >= 1; off >>= 1) s += __shfl_xor(s, off);
    __syncthreads();
    if (lane == 0) red[2+w] = s;
    __syncthreads();
    const float inv_s = 1.0f / (red[2] + red[3]);
    alpha[tid]      = e0 * inv_s;
    alpha[tid+128]  = e1 * inv_s;

    // ---- hoisted MFMA fragments ----
    const int kbase = (lane >> 4) * 8;     // k-slot base (same map for A and B)
    float rw1q[8], rb1q[8];
    #pragma unroll
    for (int q = 0; q < 8; ++q) { rw1q[q] = Rw1[kbase+q]; rb1q[q] = Rb1[kbase+q]; }

    short8 bfrag[4];
    f32x4 cinit[4];
    const int colbase = w * 64;
    #pragma unroll
    for (int t = 0; t < 4; ++t) {
        const int col = colbase + t*16 + (lane & 15);
        #pragma unroll
        for (int q = 0; q < 8; ++q)
            bfrag[t][q] = f2bf(Rw2[(kbase+q)*LC + col]);
        const float rb = Rb2[col];
        cinit[t] = (f32x4){rb, rb, rb, rb};
    }

    float acc[8] = {0,0,0,0,0,0,0,0};

    for (int j0 = 0; j0 < NN; j0 += 16) {
        __syncthreads();   // previous consumers done; r_lds/alpha ready on iter 0

        // ---- Y staging: 16 threads, one j each, padded slot layout ----
        if (tid < 16) {
            const int j = j0 + tid;
            const float dx = xg[(rowbase+j)*4+0] - cix;
            const float dy = xg[(rowbase+j)*4+1] - ciy;
            const float dz = xg[(rowbase+j)*4+2] - ciz;
            const float ir = 1.0f / r_lds[j];
            const float ux = dx*ir, uy = dy*ir, uz = dz*ir;
            const float X2 = ux*ux, Y2 = uy*uy, Z2 = uz*uz;
            float* Y = ys2[tid];
            Y[0]  = 0.28209479f;
            Y[8]  = 0.48860251f*uy; Y[9] = 0.48860251f*uz; Y[10] = 0.48860251f*ux;
            Y[16] = 1.09254843f*ux*uy;
            Y[17] = 1.09254843f*uy*uz;
            Y[18] = 0.31539157f*(3.f*Z2 - 1.f);
            Y[19] = 1.09254843f*ux*uz;
            Y[20] = 0.54627422f*(X2 - Y2);
            Y[24] = 0.59004359f*uy*(3.f*X2 - Y2);
            Y[25] = 2.89061144f*ux*uy*uz;
            Y[26] = 0.45704579f*uy*(5.f*Z2 - 1.f);
            Y[27] = 0.37317633f*uz*(5.f*Z2 - 3.f);
            Y[28] = 0.45704579f*ux*(5.f*Z2 - 1.f);
            Y[29] = 1.44530572f*uz*(X2 - Y2);
            Y[30] = 0.59004359f*ux*(X2 - 3.f*Y2);
        }

        // ---- A fragment in registers, 4 MFMAs, scatter R to padded LDS ----
        {
            const float rj = r_lds[j0 + (lane & 15)];
            short8 afrag;
            #pragma unroll
            for (int q = 0; q < 8; ++q)
                afrag[q] = f2bf(fmaxf(rj*rw1q[q] + rb1q[q], 0.f));
            #pragma unroll
            for (int t = 0; t < 4; ++t) {
                f32x4 d = __builtin_amdgcn_mfma_f32_16x16x32_bf16(afrag, bfrag[t], cinit[t], 0, 0, 0);
                const int colw = colbase + t*16 + (lane & 15);
                #pragma unroll
                for (int q = 0; q < 4; ++q)
                    R_lds[(lane>>4)*4 + q][colw] = d[q];
            }
        }
        __syncthreads();

        // ---- consume 16 j's ----
        const float* vptr = &valsg[(l*BN + rowbase + j0)*CC + c];
        #pragma unroll
        for (int jj = 0; jj < 16; ++jj) {
            const float Rv = R_lds[jj][tid];
            const float vv = vptr[jj*CC];
            const float tf = alpha[j0+jj] * Rv * vv;
            const f32x4 y0 = *(const f32x4*)&ys2[jj][l*8];
            const f32x4 y1 = *(const f32x4*)&ys2[jj][l*8+4];
            acc[0] += tf*y0[0]; acc[1] += tf*y0[1]; acc[2] += tf*y0[2]; acc[3] += tf*y0[3];
            acc[4] += tf*y1[0]; acc[5] += tf*y1[1]; acc[6] += tf*y1[2]; acc[7] += tf*y1[3];
        }
    }

    float ssum = 1e-8f;
    #pragma unroll
    for (int mm = 0; mm < 7; ++mm)
        if (mm < nm) ssum += acc[mm]*acc[mm];
    invg[bi*LC + tid] = sqrtf(ssum);
}

// ---------------- Kernel C: pool + fc1 + LN + relu + fc2 ----------------
__global__ __launch_bounds__(256) void so3_post(
    const float* __restrict__ invg,   // (B,N,128)
    const float* __restrict__ fc1_w,  // (256,256)
    const float* __restrict__ fc1_b,  // (256)
    const float* __restrict__ ln_g,   // (256)
    const float* __restrict__ ln_b,   // (256)
    const float* __restrict__ fc2_w,  // (256,40)
    const float* __restrict__ fc2_b,  // (40)
    float* __restrict__ outg)         // (B,40)
{
    const int b = blockIdx.x;
    const int t = threadIdx.x;
    __shared__ float pooled[256];
    __shared__ float h1s[256];
    __shared__ float redA[4], redB[4];

    if (t < 128) {
        float mx = -1e30f, sm = 0.f;
        for (int i = 0; i < NN; ++i) {
            const float v = invg[(b*NN + i)*LC + t];
            mx = fmaxf(mx, v);
            sm += v;
        }
        pooled[t] = mx;
        pooled[128 + t] = sm * (1.f/256.f);
    }
    __syncthreads();

    float acc = fc1_b[t];
    for (int k = 0; k < 256; ++k)
        acc += pooled[k] * fc1_w[k*256 + t];

    const int lane = t & 63, wid = t >> 6;
    float s1 = acc, s2 = acc*acc;
    #pragma unroll
    for (int off = 32; off >= 1; off >>= 1) {
        s1 += __shfl_xor(s1, off);
        s2 += __shfl_xor(s2, off);
    }
    if (lane == 0) { redA[wid] = s1; redB[wid] = s2; }
    __syncthreads();
    s1 = redA[0]+redA[1]+redA[2]+redA[3];
    s2 = redB[0]+redB[1]+redB[2]+redB[3];
    const float mu = s1 * (1.f/256.f);
    const float var = s2 * (1.f/256.f) - mu*mu;
    float v = (acc - mu) * rsqrtf(var + 1e-5f) * ln_g[t] + ln_b[t];
    v = fmaxf(v, 0.f);
    h1s[t] = v;
    __syncthreads();

    if (t < 40) {
        float o = fc2_b[t];
        for (int k = 0; k < 256; ++k)
            o += h1s[k] * fc2_w[k*40 + t];
        outg[b*40 + t] = o;
    }
}

extern "C" void kernel_launch(void* const* d_in, const int* in_sizes, int n_in,
                              void* d_out, int out_size, void* d_ws, size_t ws_size,
                              hipStream_t stream) {
    const float* x     = (const float*)d_in[0];
    const float* Wq    = (const float*)d_in[1];
    const float* Wk    = (const float*)d_in[2];
    const float* Wv    = (const float*)d_in[3];
    const float* Rw1   = (const float*)d_in[4];
    const float* Rb1   = (const float*)d_in[5];
    const float* Rw2   = (const float*)d_in[6];
    const float* Rb2   = (const float*)d_in[7];
    const float* fc1_w = (const float*)d_in[8];
    const float* fc1_b = (const float*)d_in[9];
    const float* ln_g  = (const float*)d_in[10];
    const float* ln_b  = (const float*)d_in[11];
    const float* fc2_w = (const float*)d_in[12];
    const float* fc2_b = (const float*)d_in[13];
    float* out = (float*)d_out;

    float* ws = (float*)d_ws;
    float* qg    = ws;                    // 65536
    float* kg    = qg + BN*CC;            // 65536
    float* valsg = kg + BN*CC;            // 262144
    float* invg  = valsg + LL*BN*CC;      // 262144

    so3_pre <<<BN, 192, 0, stream>>>(x, Wq, Wk, Wv, qg, kg, valsg);
    so3_main<<<BN, 128, 0, stream>>>(x, qg, kg, valsg, Rw1, Rb1, Rw2, Rb2, invg);
    so3_post<<<BB, 256, 0, stream>>>(invg, fc1_w, fc1_b, ln_g, ln_b, fc2_w, fc2_b, out);
}

// Round 3
// 64.285 us; speedup vs baseline: 3.1213x; 1.1993x over previous
//
#include <hip/hip_runtime.h>
#include <hip/hip_bf16.h>

#define BB 8
#define NN 256
#define CC 32
#define LL 4
#define BN (BB*NN)          // 2048
#define LC (LL*CC)          // 128

typedef short short8 __attribute__((ext_vector_type(8)));
typedef float f32x4 __attribute__((ext_vector_type(4)));

union U8 { short8 s; unsigned u[4]; };

__device__ inline unsigned pkbf(float a, float b){
    __hip_bfloat162 h = __float22bfloat162_rn(make_float2(a, b));
    union { __hip_bfloat162 h2; unsigned u; } cv; cv.h2 = h; return cv.u;
}

// ---------------- Kernel A: precompute q, k, vals ----------------
__global__ __launch_bounds__(192) void so3_pre(
    const float* __restrict__ xg,   // (B,N,4)
    const float* __restrict__ Wq,   // (4,32)
    const float* __restrict__ Wk,   // (4,32)
    const float* __restrict__ Wv,   // (L,4,32)
    float* __restrict__ qg,         // (B,N,32)
    float* __restrict__ kg,         // (B,N,32)
    float* __restrict__ valsg)      // (L,B,N,32)
{
    const int row = blockIdx.x;     // b*N + j
    const int t = threadIdx.x;
    const float x0 = xg[row*4+0], x1 = xg[row*4+1], x2 = xg[row*4+2], x3 = xg[row*4+3];
    if (t < 64) {
        const float* W = (t < 32) ? Wq : Wk;
        const int c = t & 31;
        float a = x0*W[c] + x1*W[32+c] + x2*W[64+c] + x3*W[96+c];
        if (t < 32) qg[row*32+c] = a; else kg[row*32+c] = a;
    } else {
        const int idx = t - 64;                 // 0..127
        const int l = idx >> 5, c = idx & 31;
        const float* W = Wv + l*128;            // (4,32) slab
        float a = x0*W[c] + x1*W[32+c] + x2*W[64+c] + x3*W[96+c];
        valsg[(l*BN + row)*CC + c] = a;
    }
}

// ---------------- Kernel B: main per-(b,i), dual MFMA ----------------
__global__ __launch_bounds__(128, 4) void so3_main(
    const float* __restrict__ xg,     // (B,N,4)
    const float* __restrict__ qg,     // (B,N,32)
    const float* __restrict__ kg,     // (B,N,32)
    const float* __restrict__ valsg,  // (L,B,N,32)
    const float* __restrict__ Rw1,    // (32)
    const float* __restrict__ Rb1,    // (32)
    const float* __restrict__ Rw2,    // (32,128)
    const float* __restrict__ Rb2,    // (128)
    float* __restrict__ invg)         // (B,N,128)
{
    const int tid = threadIdx.x;          // 0..127
    const int bi = blockIdx.x;            // b*N + i
    const int b = bi >> 8;
    const int rowbase = b * NN;
    const int lane = tid & 63;
    const int w = tid >> 6;               // wave 0/1
    const int n = lane & 15;              // frag row/col
    const int g = lane >> 4;              // k-group
    const int kbase = g * 8;

    __shared__ short G_t[128*40];         // G=R*v, bf16, [c][j-slot] stride 40
    __shared__ short aY[16*264];          // alpha*Y, bf16, [msl][j] stride 264
    __shared__ float r_lds[NN];           // also reused as ssum in epilogue
    __shared__ float qs[CC];
    __shared__ float red[4];

    const float4 xi = *(const float4*)&xg[bi*4];
    const float cix = xi.x, ciy = xi.y, ciz = xi.z;

    // ---- r + stash d for Y staging (j = tid, tid+128) ----
    float dx0, dy0, dz0, r20, dx1, dy1, dz1, r21;
    {
        const float4 xa = *(const float4*)&xg[(rowbase + tid)*4];
        dx0 = xa.x - cix; dy0 = xa.y - ciy; dz0 = xa.z - ciz;
        r20 = dx0*dx0 + dy0*dy0 + dz0*dz0 + 1e-8f;
        r_lds[tid] = sqrtf(r20);
        const float4 xb = *(const float4*)&xg[(rowbase + tid + 128)*4];
        dx1 = xb.x - cix; dy1 = xb.y - ciy; dz1 = xb.z - ciz;
        r21 = dx1*dx1 + dy1*dy1 + dz1*dz1 + 1e-8f;
        r_lds[tid+128] = sqrtf(r21);
    }
    if (tid < 32) qs[tid] = qg[bi*32 + tid];
    __syncthreads();

    // ---- logits + softmax ----
    float lg0, lg1;
    {
        float lv[2];
        #pragma unroll
        for (int rr = 0; rr < 2; ++rr) {
            const int j = tid + rr*128;
            const float4* krow = reinterpret_cast<const float4*>(&kg[(rowbase + j)*32]);
            float a = 0.f;
            #pragma unroll
            for (int c4 = 0; c4 < 8; ++c4) {
                float4 kv = krow[c4];
                a += kv.x*qs[c4*4+0] + kv.y*qs[c4*4+1] + kv.z*qs[c4*4+2] + kv.w*qs[c4*4+3];
            }
            lv[rr] = a * 0.17677669529663687f;
        }
        lg0 = lv[0]; lg1 = lv[1];
    }
    float m = fmaxf(lg0, lg1);
    #pragma unroll
    for (int off = 32; off >= 1; off >>= 1) m = fmaxf(m, __shfl_xor(m, off));
    if (lane == 0) red[w] = m;
    __syncthreads();
    m = fmaxf(red[0], red[1]);
    float e0 = __expf(lg0 - m), e1 = __expf(lg1 - m);
    float s = e0 + e1;
    #pragma unroll
    for (int off = 32; off >= 1; off >>= 1) s += __shfl_xor(s, off);
    __syncthreads();
    if (lane == 0) red[2+w] = s;
    __syncthreads();
    const float inv_s = 1.0f / (red[2] + red[3]);
    const float alpha0 = e0 * inv_s;
    const float alpha1 = e1 * inv_s;

    // ---- stage aY = alpha * Y (bf16), columns j=tid, tid+128 ----
    #pragma unroll
    for (int rr = 0; rr < 2; ++rr) {
        const int j = tid + rr*128;
        const float a = rr ? alpha1 : alpha0;
        const float dx = rr ? dx1 : dx0, dy = rr ? dy1 : dy0, dz = rr ? dz1 : dz0;
        const float r2 = rr ? r21 : r20;
        const float ir = rsqrtf(r2);
        const float ux = dx*ir, uy = dy*ir, uz = dz*ir;
        const float X2 = ux*ux, Y2 = uy*uy, Z2 = uz*uz;
        const float y0  = 0.28209479f;
        const float y1  = 0.48860251f*uy, y2 = 0.48860251f*uz, y3 = 0.48860251f*ux;
        const float y4  = 1.09254843f*ux*uy;
        const float y5  = 1.09254843f*uy*uz;
        const float y6  = 0.31539157f*(3.f*Z2 - 1.f);
        const float y7  = 1.09254843f*ux*uz;
        const float y8  = 0.54627422f*(X2 - Y2);
        const float y9  = 0.59004359f*uy*(3.f*X2 - Y2);
        const float y10 = 2.89061144f*ux*uy*uz;
        const float y11 = 0.45704579f*uy*(5.f*Z2 - 1.f);
        const float y12 = 0.37317633f*uz*(5.f*Z2 - 3.f);
        const float y13 = 0.45704579f*ux*(5.f*Z2 - 1.f);
        const float y14 = 1.44530572f*uz*(X2 - Y2);
        const float y15 = 0.59004359f*ux*(X2 - 3.f*Y2);
        #define ST2(mm, va, vb) { unsigned uu = pkbf((va)*a, (vb)*a); \
            aY[(mm)*264 + j] = (short)(uu & 0xffff); aY[(mm+1)*264 + j] = (short)(uu >> 16); }
        ST2(0,  y0,  y1)  ST2(2,  y2,  y3)
        ST2(4,  y4,  y5)  ST2(6,  y6,  y7)
        ST2(8,  y8,  y9)  ST2(10, y10, y11)
        ST2(12, y12, y13) ST2(14, y14, y15)
        #undef ST2
    }

    // ---- hoisted GEMM1 fragments ----
    float rw1q[8], rb1q[8];
    #pragma unroll
    for (int q = 0; q < 8; ++q) { rw1q[q] = Rw1[kbase+q]; rb1q[q] = Rb1[kbase+q]; }

    short8 bfrag[4];
    f32x4 cinit[4];
    const int colbase = w * 64;
    #pragma unroll
    for (int t4 = 0; t4 < 4; ++t4) {
        const int col = colbase + t4*16 + n;
        U8 bf;
        #pragma unroll
        for (int qq = 0; qq < 4; ++qq)
            bf.u[qq] = pkbf(Rw2[(kbase+2*qq)*LC + col], Rw2[(kbase+2*qq+1)*LC + col]);
        bfrag[t4] = bf.s;
        const float rb = Rb2[col];
        cinit[t4] = (f32x4){rb, rb, rb, rb};
    }

    // ---- hoisted GEMM2 addresses ----
    const int l0 = 2*w;
    int offA[2][2], offB[2];
    #pragma unroll
    for (int li = 0; li < 2; ++li) {
        const int l = l0 + li;
        offB[li] = (l*l + (n < 2*l ? n : 2*l)) * 264 + kbase;
        #pragma unroll
        for (int ch = 0; ch < 2; ++ch)
            offA[li][ch] = (l*32 + ch*16 + n) * 40 + kbase;
    }

    f32x4 acc2[2][2] = {};

    for (int j0 = 0; j0 < NN; j0 += 32) {
        __syncthreads();   // prev consume done; first iter: aY/r_lds ready

        // ---- GEMM1 (H @ Rw2 + Rb2) * vals -> G_t (bf16, transposed) ----
        #pragma unroll
        for (int jh = 0; jh < 2; ++jh) {
            const float rj = r_lds[j0 + jh*16 + n];
            U8 af;
            #pragma unroll
            for (int qq = 0; qq < 4; ++qq) {
                const float h0 = fmaxf(rj*rw1q[2*qq]   + rb1q[2*qq],   0.f);
                const float h1 = fmaxf(rj*rw1q[2*qq+1] + rb1q[2*qq+1], 0.f);
                af.u[qq] = pkbf(h0, h1);
            }
            #pragma unroll
            for (int t4 = 0; t4 < 4; ++t4) {
                f32x4 d = __builtin_amdgcn_mfma_f32_16x16x32_bf16(af.s, bfrag[t4], cinit[t4], 0, 0, 0);
                const int colw = colbase + t4*16 + n;
                const int lv = colw >> 5, cv = colw & 31;
                const float* vb = &valsg[(lv*BN + rowbase + j0 + jh*16 + 4*g)*CC + cv];
                const float v0 = vb[0], v1 = vb[CC], v2 = vb[2*CC], v3 = vb[3*CC];
                const unsigned g01 = pkbf(d[0]*v0, d[1]*v1);
                const unsigned g23 = pkbf(d[2]*v2, d[3]*v3);
                *(uint2*)&G_t[colw*40 + jh*16 + 4*g] = make_uint2(g01, g23);
            }
        }
        __syncthreads();   // G_t ready

        // ---- GEMM2: acc[c][m] += G^T[c][j] @ aY[j][m] ----
        #pragma unroll
        for (int li = 0; li < 2; ++li) {
            const short8 b2 = *(const short8*)&aY[offB[li] + j0];
            #pragma unroll
            for (int ch = 0; ch < 2; ++ch) {
                const short8 a2 = *(const short8*)&G_t[offA[li][ch]];
                acc2[li][ch] = __builtin_amdgcn_mfma_f32_16x16x32_bf16(a2, b2, acc2[li][ch], 0, 0, 0);
            }
        }
    }

    // ---- epilogue: ssum over m, write invariants ----
    float* ssum_lds = r_lds;   // safe: r_lds last read before final barrier
    #pragma unroll
    for (int li = 0; li < 2; ++li) {
        const int l = l0 + li;
        const bool valid = (n <= 2*l);
        #pragma unroll
        for (int ch = 0; ch < 2; ++ch) {
            f32x4 aq = acc2[li][ch];
            float s0 = valid ? aq[0]*aq[0] : 0.f;
            float s1 = valid ? aq[1]*aq[1] : 0.f;
            float s2 = valid ? aq[2]*aq[2] : 0.f;
            float s3 = valid ? aq[3]*aq[3] : 0.f;
            #pragma unroll
            for (int off = 1; off <= 8; off <<= 1) {
                s0 += __shfl_xor(s0, off);
                s1 += __shfl_xor(s1, off);
                s2 += __shfl_xor(s2, off);
                s3 += __shfl_xor(s3, off);
            }
            const float sv = (n==0) ? s0 : ((n==1) ? s1 : ((n==2) ? s2 : s3));
            if (n < 4) ssum_lds[l*32 + ch*16 + g*4 + n] = sv;
        }
    }
    __syncthreads();
    invg[bi*LC + tid] = sqrtf(ssum_lds[tid] + 1e-8f);
}

// ---------------- Kernel C: pool + fc1 + LN + relu + fc2 ----------------
__global__ __launch_bounds__(512) void so3_post(
    const float* __restrict__ invg,   // (B,N,128)
    const float* __restrict__ fc1_w,  // (256,256)
    const float* __restrict__ fc1_b,  // (256)
    const float* __restrict__ ln_g,   // (256)
    const float* __restrict__ ln_b,   // (256)
    const float* __restrict__ fc2_w,  // (256,40)
    const float* __restrict__ fc2_b,  // (40)
    float* __restrict__ outg)         // (B,40)
{
    const int b = blockIdx.x;
    const int t = threadIdx.x;
    __shared__ float pmax[4][128], psum[4][128];
    __shared__ float pooled[256];
    __shared__ float pfc1[2][256];
    __shared__ float h1s[256];
    __shared__ float pf2[8][40];
    __shared__ float redA[8], redB[8];

    // pooling: 4-way i-split
    {
        const int ig = t >> 7, lc = t & 127;
        float mx = -1e30f, sm = 0.f;
        for (int i = ig; i < NN; i += 4) {
            const float v = invg[(b*NN + i)*LC + lc];
            mx = fmaxf(mx, v);
            sm += v;
        }
        pmax[ig][lc] = mx; psum[ig][lc] = sm;
    }
    __syncthreads();
    if (t < 128) {
        pooled[t] = fmaxf(fmaxf(pmax[0][t], pmax[1][t]), fmaxf(pmax[2][t], pmax[3][t]));
    } else if (t < 256) {
        const int lc = t - 128;
        pooled[t] = (psum[0][lc] + psum[1][lc] + psum[2][lc] + psum[3][lc]) * (1.f/256.f);
    }
    __syncthreads();

    // fc1: 2-way k-split
    {
        const int o = t & 255, kh = t >> 8;
        float acc = 0.f;
        for (int k = kh*128; k < kh*128 + 128; ++k)
            acc += pooled[k] * fc1_w[k*256 + o];
        pfc1[kh][o] = acc;
    }
    __syncthreads();

    float hval = 0.f;
    if (t < 256) hval = pfc1[0][t] + pfc1[1][t] + fc1_b[t];

    const int lane = t & 63, wid = t >> 6;
    float s1 = hval, s2 = hval*hval;
    #pragma unroll
    for (int off = 32; off >= 1; off >>= 1) {
        s1 += __shfl_xor(s1, off);
        s2 += __shfl_xor(s2, off);
    }
    if (lane == 0) { redA[wid] = s1; redB[wid] = s2; }
    __syncthreads();
    s1 = redA[0]+redA[1]+redA[2]+redA[3];
    s2 = redB[0]+redB[1]+redB[2]+redB[3];
    if (t < 256) {
        const float mu = s1 * (1.f/256.f);
        const float var = s2 * (1.f/256.f) - mu*mu;
        float v = (hval - mu) * rsqrtf(var + 1e-5f) * ln_g[t] + ln_b[t];
        h1s[t] = fmaxf(v, 0.f);
    }
    __syncthreads();

    // fc2: 8-way k-split over 320 threads
    if (t < 320) {
        const int o = t % 40, ks = t / 40;
        float acc = 0.f;
        for (int k = ks*32; k < ks*32 + 32; ++k)
            acc += h1s[k] * fc2_w[k*40 + o];
        pf2[ks][o] = acc;
    }
    __syncthreads();
    if (t < 40) {
        float o = fc2_b[t];
        #pragma unroll
        for (int ks = 0; ks < 8; ++ks) o += pf2[ks][t];
        outg[b*40 + t] = o;
    }
}

extern "C" void kernel_launch(void* const* d_in, const int* in_sizes, int n_in,
                              void* d_out, int out_size, void* d_ws, size_t ws_size,
                              hipStream_t stream) {
    const float* x     = (const float*)d_in[0];
    const float* Wq    = (const float*)d_in[1];
    const float* Wk    = (const float*)d_in[2];
    const float* Wv    = (const float*)d_in[3];
    const float* Rw1   = (const float*)d_in[4];
    const float* Rb1   = (const float*)d_in[5];
    const float* Rw2   = (const float*)d_in[6];
    const float* Rb2   = (const float*)d_in[7];
    const float* fc1_w = (const float*)d_in[8];
    const float* fc1_b = (const float*)d_in[9];
    const float* ln_g  = (const float*)d_in[10];
    const float* ln_b  = (const float*)d_in[11];
    const float* fc2_w = (const float*)d_in[12];
    const float* fc2_b = (const float*)d_in[13];
    float* out = (float*)d_out;

    float* ws = (float*)d_ws;
    float* qg    = ws;                    // 65536
    float* kg    = qg + BN*CC;            // 65536
    float* valsg = kg + BN*CC;            // 262144
    float* invg  = valsg + LL*BN*CC;      // 262144

    so3_pre <<<BN, 192, 0, stream>>>(x, Wq, Wk, Wv, qg, kg, valsg);
    so3_main<<<BN, 128, 0, stream>>>(x, qg, kg, valsg, Rw1, Rb1, Rw2, Rb2, invg);
    so3_post<<<BB, 512, 0, stream>>>(invg, fc1_w, fc1_b, ln_g, ln_b, fc2_w, fc2_b, out);
}